// Round 4
// baseline (175.803 us; speedup 1.0000x reference)
//
#include <hip/hip_runtime.h>
#include <hip/hip_bf16.h>
#include <hip/hip_fp16.h>

// Problem constants (B,L,P fixed by the reference setup)
#define B_   1024
#define L_   128
#define P_   32
#define PP_  1024            // P*P
#define N_   128             // output cols = L
// Symmetry-packed K: 4x4 (i,j)-blocks, upper-triangular list (36 blocks x 16)
#define KP_  576             // packed K per l = 36 * 16 = 9 * 64
#define KT_  73728           // 128 * KP_
#define MAGIC 0x9E3779B9u    // flag value; != any plausible poison pattern

typedef float    f32x4 __attribute__((ext_vector_type(4)));
typedef _Float16 f16x8 __attribute__((ext_vector_type(8)));
typedef _Float16 f16x2 __attribute__((ext_vector_type(2)));
typedef __fp16   fp16x2_builtin __attribute__((ext_vector_type(2)));

// triangular 4x4 block table: blk -> (I<<3)|J, I<=J in 0..7
__device__ __constant__ unsigned char IJTAB[36] = {
  0,1,2,3,4,5,6,7, 9,10,11,12,13,14,15, 18,19,20,21,22,23,
  27,28,29,30,31, 36,37,38,39, 45,46,47, 54,55, 63};

// pack two f32 -> f16x2 bits in one v_cvt_pkrtz_f16_f32
static __device__ __forceinline__ unsigned int pk16(float a, float b) {
  fp16x2_builtin h = __builtin_amdgcn_cvt_pkrtz(a, b);
  return *(unsigned int*)&h;
}

// async global->LDS, 16B per lane; lds base must be wave-uniform (lane scatters
// to base + lane*16). Counts against vmcnt; __syncthreads drains it.
static __device__ __forceinline__ void gload16(void* lds, const void* g) {
  __builtin_amdgcn_global_load_lds(
      (const __attribute__((address_space(1))) unsigned int*)g,
      (__attribute__((address_space(3))) unsigned int*)lds, 16, 0, 0);
}

// Cache-neutral flag probe: a relaxed atomic RMW is forced to the device
// coherence point -- it can never be satisfied from a stale local L2 line
// (no livelock), and RELAXED ordering emits NO buffer_inv/wbl2.
// (Round-1 lesson: ACQUIRE loads in a spin = buffer_inv per poll = L2
// annihilation, 606 GB/s effective.) Opaque zero via inline asm stops LLVM
// rewriting the idempotent RMW into a plain atomic load.
static __device__ __forceinline__ unsigned int flag_probe(unsigned int* p) {
  unsigned int z;
  asm volatile("v_mov_b32 %0, 0" : "=v"(z));
  return __hip_atomic_fetch_add(p, z, __ATOMIC_RELAXED, __HIP_MEMORY_SCOPE_AGENT);
}
// One-shot release: s_waitcnt + buffer_wbl2 (push this XCD's dirty lines
// toward the device coherence point) + flag store. One per block per phase.
static __device__ __forceinline__ void flag_store_release(unsigned int* p) {
  __hip_atomic_store(p, MAGIC, __ATOMIC_RELEASE, __HIP_MEMORY_SCOPE_AGENT);
}
// One-shot acquire fence after ALL polls succeed: single buffer_inv.
// (__hip_atomic_fence does not exist; the amdgcn builtin does.)
static __device__ __forceinline__ void fence_acquire() {
  __builtin_amdgcn_fence(__ATOMIC_ACQUIRE, "agent");
}

// ---------------------------------------------------------------------------
// Single fused kernel, grid 512 x 256, 3 phases linked by device-scope flags.
// Phase bodies, unit->block mapping and wait-sets are IDENTICAL to the
// round-1 fused kernel (correctness-proven); only the sync discipline
// changed: relaxed RMW probes + s_sleep(32) + one acquire fence per block.
//
// Phase P (prep): block runs units {bid, bid+512, bid+1024} of the 1216-unit
//   prep grid (blocks 0..127: 3 W-units; 128..191: 2 W-units + interf;
//   192..511: 2 W-units). Release flagP[bid] at end.
// Phase G (gemm): block (mtile=bid>>6, kchunk=bid&63) waits on its 16
//   producers, acquire-fences once, then the split-K LPC=2 gemm body.
//   Release flagG[bid].
// Phase R (reduce): block waits on its mtile's 64 flagG (parallel probes),
//   acquire-fences once, reduces out rows 2*bid, 2*bid+1 from partials that
//   are L3-hot (no kernel-boundary round trip).
//
// MAGIC-word flags need no pre-zeroing of the poisoned ws. Stale MAGIC from
// a previous identical iteration only short-circuits waits; all phases are
// deterministic functions of the same inputs, so that is benign.
// Liveness: DAG acyclic + all 512 blocks co-resident (2/CU guaranteed by
// __launch_bounds__(256,2), 54 KiB LDS, 112 VGPR measured in round 1; round
// 1 completed = empirical liveness proof of this launch environment).
// ---------------------------------------------------------------------------
__global__ __launch_bounds__(256, 2) void fused_kernel(
    const float* __restrict__ W, const float* __restrict__ pert,
    const float* __restrict__ ctrl, const float* __restrict__ bias,
    unsigned short* __restrict__ Wt, uint4* __restrict__ interf,
    _Float16* __restrict__ partials, unsigned int* __restrict__ flagP,
    unsigned int* __restrict__ flagG, float* __restrict__ out)
{
  __shared__ unsigned int t32[32 * 133];      // prep transpose staging
  __shared__ float pl[512];                   // interf pert rows
  __shared__ unsigned short Bsm[2][128 * 64]; // gemm B tiles, 2 x 16 KiB
  __shared__ float red[4][64][2];             // reduce cross-wave

  const int bid = blockIdx.x, tid = threadIdx.x;
  const int kchunk = bid & 63, mtile = bid >> 6;

  // ============================ phase P: prep ============================
  for (int u = bid; u < 1216; u += 512) {
    __syncthreads();                          // t32 / pl reuse across units
    if (u < 1152) {
      const int q = u & 127, grp = u >> 7;    // grp 0..8
      const int l = (q & 63) * 2 + (q >> 6);
      const size_t baseL = (size_t)l * PP_;
      // phase 1: 1024 items = (sp in [0,32)) x (nq in [0,32))
      for (int i = 0; i < 4; ++i) {
        int idx = tid + i * 256;
        int sp = idx >> 5, nq = (idx & 31) * 4;
        const int s = grp * 64 + 2 * sp;      // even packed index
        const int blk = s >> 4, a = (s >> 2) & 3, c = (s >> 1) & 1;
        const int ij = IJTAB[blk], I = ij >> 3, J = ij & 7;
        const int rowX = (4 * I + a) * 32 + 4 * J + 2 * c;
        float4 s0 = *(const float4*)(W + (baseL + rowX)     * N_ + nq);
        float4 s1 = *(const float4*)(W + (baseL + rowX + 1) * N_ + nq);
        if (I != J) {
          const int rowY0 = (4 * J + 2 * c) * 32 + 4 * I + a;
          const float4 y0 = *(const float4*)(W + (baseL + rowY0)      * N_ + nq);
          const float4 y1 = *(const float4*)(W + (baseL + rowY0 + 32) * N_ + nq);
          s0.x += y0.x; s0.y += y0.y; s0.z += y0.z; s0.w += y0.w;
          s1.x += y1.x; s1.y += y1.y; s1.z += y1.z; s1.w += y1.w;
        }
        uint4 w;
        w.x = pk16(s0.x, s1.x);
        w.y = pk16(s0.y, s1.y);
        w.z = pk16(s0.z, s1.z);
        w.w = pk16(s0.w, s1.w);
        *(uint4*)&t32[sp * 133 + nq] = w;
      }
      __syncthreads();
      // phase 2: (n in [0,128)) x (cg in [0,8)): gather 4 u32 down a column
      for (int i = 0; i < 4; ++i) {
        int idx = tid + i * 256;
        int n = idx >> 3, cg = idx & 7;
        uint4 w;
        w.x = t32[(cg * 4 + 0) * 133 + n];
        w.y = t32[(cg * 4 + 1) * 133 + n];
        w.z = t32[(cg * 4 + 2) * 133 + n];
        w.w = t32[(cg * 4 + 3) * 133 + n];
        *(uint4*)(Wt + (size_t)n * KT_ + l * KP_ + grp * 64 + cg * 8) = w;
      }
    } else {
      const int mt = u - 1152;                // 0..63, 16 b-rows each
      pl[tid]       = pert[(size_t)mt * 512 + tid];
      pl[tid + 256] = pert[(size_t)mt * 512 + tid + 256];
      __syncthreads();
      for (int r = 0; r < 5; ++r) {
        const int idx = tid + r * 256;        // (k8, lm): 72*16 = 1152 items
        if (idx < 1152) {
          const int k8 = idx >> 4, lm = idx & 15;
          const int blk = k8 >> 1, a0 = 2 * (k8 & 1);
          const int ij = IJTAB[blk], I = ij >> 3, J = ij & 7;
          const float* p = &pl[lm * 32];
          const float pi0 = p[4 * I + a0], pi1 = p[4 * I + a0 + 1];
          const float* pj = p + 4 * J;
          uint4 w;
          w.x = pk16(pi0 * pj[0], pi0 * pj[1]);
          w.y = pk16(pi0 * pj[2], pi0 * pj[3]);
          w.z = pk16(pi1 * pj[0], pi1 * pj[1]);
          w.w = pk16(pi1 * pj[2], pi1 * pj[3]);
          interf[(size_t)mt * 1152 + idx] = w;
        }
      }
    }
  }
  __syncthreads();              // all threads' stores vmcnt-drained to L2
  if (tid == 0) flag_store_release(&flagP[bid]);   // one wbl2 + flag

  // ===================== wait for the 16 producers =======================
  // tid<16 probe one producer each (parallel, latency-hidden); relaxed RMW
  // probes + s_sleep(32) -> zero cache maintenance while spinning.
  if (tid < 16) {
    int prod;
    if (tid < 4)      prod = kchunk + tid * 128;             // Wt l0, grps 0-8
    else if (tid < 8) prod = kchunk + 64 + (tid - 4) * 128;  // Wt l1, grps 0-8
    else              prod = 128 + mtile * 8 + (tid - 8);    // interf mts
    while (flag_probe(&flagP[prod]) != MAGIC) __builtin_amdgcn_s_sleep(32);
  }
  __syncthreads();
  if (tid == 0) fence_acquire();              // ONE buffer_inv per block
  __syncthreads();

  // ============================ phase G: gemm ============================
  {
    const int m0 = mtile * 128;
    const int l0 = kchunk * 2;
    const int lane = tid & 63, wid = tid >> 6;
    const int wm = (wid >> 1) * 64, wn = (wid & 1) * 64;
    const int lm = lane & 15, kq = lane >> 4;

    // B staging geometry: lane covers (row = 8j+srow, chunk c8) in its segment
    const int srow = lane >> 3, c8 = lane & 7;
    const int sc = (c8 ^ srow) * 8;            // source elem offset (XOR swizzle)

    const unsigned short* bg0[4]; const unsigned short* bg1[4];
    unsigned short* bl0[4];       unsigned short* bl1[4];
    for (int j = 0; j < 4; ++j) {              // wave stages 32 B-rows per l
      const int rr = wid * 32 + j * 8;
      bg0[j] = Wt + (size_t)(rr + srow) * KT_ + (size_t)l0 * KP_ + sc;
      bg1[j] = bg0[j] + KP_;
      bl0[j] = &Bsm[0][rr * 64];
      bl1[j] = &Bsm[1][rr * 64];
    }

    // A fragment pointers: m-frag-block MT = mtile*8 + (wid>>1)*4 + tm
    const uint4* ap[4];
    for (int tm = 0; tm < 4; ++tm)
      ap[tm] = interf + (size_t)(mtile * 8 + (wid >> 1) * 4 + tm) * 1152 + lane;

    f32x4 acc[2][4][4];
    for (int li = 0; li < 2; ++li)
      for (int tm = 0; tm < 4; ++tm)
        for (int tn = 0; tn < 4; ++tn)
          acc[li][tm][tn] = (f32x4){0.f, 0.f, 0.f, 0.f};

    for (int it = 0; it < 9; ++it) {        // 9 * BK=64 = 576 = one packed l
      const int q0 = it * 64;
      __syncthreads();                      // previous iter's LDS reads done
      // A fragments (shared by both l's), global->VGPR
      f16x8 af[2][4];
      for (int ks = 0; ks < 2; ++ks)
        for (int tm = 0; tm < 4; ++tm)
          af[ks][tm] = *(const f16x8*)(ap[tm] + it * 128 + ks * 64);
      // B tiles for l0 and l1, global->LDS DMA
      for (int j = 0; j < 4; ++j) gload16(bl0[j], bg0[j] + q0);
      for (int j = 0; j < 4; ++j) gload16(bl1[j], bg1[j] + q0);
      __syncthreads();                      // drains vmcnt -> af + LDS valid
      for (int ks = 0; ks < 2; ++ks) {
        const int ch = (((ks * 4 + kq) ^ (lm & 7)) * 8);   // swizzled chunk
        for (int li = 0; li < 2; ++li) {
          f16x8 bfr[4];
          for (int t = 0; t < 4; ++t)
            bfr[t] = *(const f16x8*)&Bsm[li][(wn + t * 16 + lm) * 64 + ch];
          for (int tm = 0; tm < 4; ++tm)
            for (int t = 0; t < 4; ++t)
              acc[li][tm][t] = __builtin_amdgcn_mfma_f32_16x16x32_f16(
                  af[ks][tm], bfr[t], acc[li][tm][t], 0, 0, 0);
        }
      }
    }

    // epilogue: fold ctrl for both l's, store fp16 partial tile (128x128).
    // C/D layout: row = kq*4+reg, col = lm (m89-verified).
    _Float16* pb = partials + (size_t)bid * (128 * 128);
    for (int tm = 0; tm < 4; ++tm)
      for (int reg = 0; reg < 4; ++reg) {
        const int row = wm + tm * 16 + kq * 4 + reg;
        const float c0v = ctrl[(size_t)(m0 + row) * L_ + l0];
        const float c1v = ctrl[(size_t)(m0 + row) * L_ + l0 + 1];
        for (int tn = 0; tn < 4; ++tn)
          pb[row * 128 + wn + tn * 16 + lm] = (_Float16)(
              c0v * acc[0][tm][tn][reg] + c1v * acc[1][tm][tn][reg]);
      }
  }
  __syncthreads();              // partial stores vmcnt-drained to L2
  if (tid == 0) flag_store_release(&flagG[bid]);   // one wbl2 + flag

  // ================ wait for this mtile's 64 gemm blocks =================
  if (tid < 64) {
    while (flag_probe(&flagG[mtile * 64 + tid]) != MAGIC)
      __builtin_amdgcn_s_sleep(32);
  }
  __syncthreads();
  if (tid == 0) fence_acquire();              // ONE buffer_inv per block
  __syncthreads();

  // =========================== phase R: reduce ===========================
  {
    const int lane = tid & 63, w = tid >> 6;
    const _Float16* pbase = partials + ((size_t)mtile * 64) * 16384;
    for (int rr = 0; rr < 2; ++rr) {
      const int g = bid * 2 + rr;             // global output row
      const int row = g & 127;                // row within 128x128 tiles
      float s0 = 0.f, s1 = 0.f;
      #pragma unroll 8
      for (int i = 0; i < 16; ++i) {
        const int sp = w + i * 4;             // kchunk 0..63
        f16x2 v = *(const f16x2*)(pbase + ((size_t)sp << 14) + row * 128 + lane * 2);
        s0 += (float)v[0];
        s1 += (float)v[1];
      }
      red[w][lane][0] = s0;
      red[w][lane][1] = s1;
      __syncthreads();
      if (w == 0) {
        float r0 = red[0][lane][0] + red[1][lane][0] + red[2][lane][0] + red[3][lane][0];
        float r1 = red[0][lane][1] + red[1][lane][1] + red[2][lane][1] + red[3][lane][1];
        r0 += bias[lane * 2];
        r1 += bias[lane * 2 + 1];
        float2 o; o.x = r0; o.y = r1;
        *(float2*)(out + (size_t)g * N_ + lane * 2) = o;
      }
      __syncthreads();                        // red reuse for rr=1
    }
  }
}

// ---------------------------------------------------------------------------
// Fallback (only if ws too small): exact fp32, slow but correct.
// ---------------------------------------------------------------------------
__global__ __launch_bounds__(256) void naive_kernel(
    const float* __restrict__ ctrl, const float* __restrict__ pert,
    const float* __restrict__ W, const float* __restrict__ bias,
    float* __restrict__ out)
{
  __shared__ float red[256];
  __shared__ float pl[P_];
  __shared__ float cl[L_];
  const int b = blockIdx.x, t = threadIdx.x;
  if (t < P_)  pl[t] = pert[(size_t)b * P_ + t];
  if (t < L_)  cl[t] = ctrl[(size_t)b * L_ + t];
  __syncthreads();
  const int m = t & 127, half = t >> 7;
  float acc = 0.f;
  for (int l = 0; l < L_; ++l) {
    float c = cl[l];
    for (int qq = half * 512; qq < half * 512 + 512; ++qq) {
      float x = c * pl[qq >> 5] * pl[qq & 31];
      acc += x * W[((size_t)l * PP_ + qq) * N_ + m];
    }
  }
  red[t] = acc;
  __syncthreads();
  if (t < 128) out[(size_t)b * 128 + t] = red[t] + red[t + 128] + bias[t];
}

extern "C" void kernel_launch(void* const* d_in, const int* in_sizes, int n_in,
                              void* d_out, int out_size, void* d_ws, size_t ws_size,
                              hipStream_t stream) {
  const float* ctrl = (const float*)d_in[0];   // (1024,128)
  const float* pert = (const float*)d_in[1];   // (1024,32)
  const float* W    = (const float*)d_in[2];   // (131072,128)
  const float* bias = (const float*)d_in[3];   // (128,)
  float* out = (float*)d_out;                  // (1024,128) fp32

  const size_t offWt    = 0;                        // 18 MiB: Wt fp16 (128,KT_)
  const size_t offInter = (size_t)18 << 20;         // 1.125 MiB: inter_f fp16
  const size_t offPart  = (size_t)20 << 20;         // 16 MiB: partials fp16
  const size_t offFlagP = (size_t)36 << 20;         // 2 KiB: flagP[512]
  const size_t offFlagG = offFlagP + 4096;          // 2 KiB: flagG[512]
  const size_t needWs   = offFlagG + 4096;

  if (ws_size >= needWs) {
    unsigned short* Wt    = (unsigned short*)((char*)d_ws + offWt);
    uint4*          intf  = (uint4*)((char*)d_ws + offInter);
    _Float16*       parts = (_Float16*)((char*)d_ws + offPart);
    unsigned int*   flagP = (unsigned int*)((char*)d_ws + offFlagP);
    unsigned int*   flagG = (unsigned int*)((char*)d_ws + offFlagG);

    fused_kernel<<<512, 256, 0, stream>>>(W, pert, ctrl, bias,
                                          Wt, intf, parts, flagP, flagG, out);
  } else {
    naive_kernel<<<1024, 256, 0, stream>>>(ctrl, pert, W, bias, out);
  }
}

// Round 5
// 128.179 us; speedup vs baseline: 1.3715x; 1.3715x over previous
//
#include <hip/hip_runtime.h>
#include <hip/hip_bf16.h>
#include <hip/hip_fp16.h>

// Problem constants (B,L,P fixed by the reference setup)
#define B_   1024
#define L_   128
#define P_   32
#define PP_  1024            // P*P
#define N_   128             // output cols = L
// Symmetry-packed K: 4x4 (i,j)-blocks, upper-triangular list (36 blocks x 16)
#define KP_  576             // packed K per l = 36 * 16 = 9 * 64
#define KT_  73728           // 128 * KP_

typedef float    f32x4 __attribute__((ext_vector_type(4)));
typedef _Float16 f16x8 __attribute__((ext_vector_type(8)));
typedef _Float16 f16x2 __attribute__((ext_vector_type(2)));
typedef __fp16   fp16x2_builtin __attribute__((ext_vector_type(2)));

// triangular 4x4 block table: blk -> (I<<3)|J, I<=J in 0..7
__device__ __constant__ unsigned char IJTAB[36] = {
  0,1,2,3,4,5,6,7, 9,10,11,12,13,14,15, 18,19,20,21,22,23,
  27,28,29,30,31, 36,37,38,39, 45,46,47, 54,55, 63};

// pack two f32 -> f16x2 bits in one v_cvt_pkrtz_f16_f32
static __device__ __forceinline__ unsigned int pk16(float a, float b) {
  fp16x2_builtin h = __builtin_amdgcn_cvt_pkrtz(a, b);
  return *(unsigned int*)&h;
}

// async global->LDS, 16B per lane; lds base must be wave-uniform (lane scatters
// to base + lane*16). Counts against vmcnt; __syncthreads drains it.
static __device__ __forceinline__ void gload16(void* lds, const void* g) {
  __builtin_amdgcn_global_load_lds(
      (const __attribute__((address_space(1))) unsigned int*)g,
      (__attribute__((address_space(3))) unsigned int*)lds, 16, 0, 0);
}

// ---------------------------------------------------------------------------
// Prep: blocks [0,1152): symmetrize+transpose W. Block d = grp*128 + q with
//   l = (q&63)*2 + (q>>6)  — this permutation puts l's writer on XCD
//   (l>>1)%8 = q%8, the SAME XCD as the gemm block (kchunk = l>>1) that
//   reads it. For packed s=16*blk+4a+b (I<=J): Wsym = W[l,(4I+a)*32+4J+b,n]
//   (+ W[l,(4J+b)*32+4I+a,n] if I<J), fp32 add -> fp16 k-pair pack (u32
//   trick) -> LDS transpose -> Wt[n][l*576 + s].
// blocks [1152,1216): inter_f in MFMA-A-FRAGMENT order: block mt (16 b-rows):
//   uint4[mt*1152 + k8*16 + lm] = frag bytes for (m=mt*16+lm, k octet k8), so
//   the gemm's A-load is base + lane*16 (dense 1 KB per wave instruction).
// ---------------------------------------------------------------------------
__global__ __launch_bounds__(256) void prep_kernel(
    const float* __restrict__ W, const float* __restrict__ pert,
    unsigned short* __restrict__ Wt, uint4* __restrict__ interf)
{
  const int bid = blockIdx.x, tid = threadIdx.x;
  __shared__ unsigned int t32[32 * 133];      // 32 s-pairs x 128 n (+5 pad)
  if (bid < 1152) {
    const int q = bid & 127, grp = bid >> 7;  // grp 0..8
    const int l = (q & 63) * 2 + (q >> 6);
    const size_t baseL = (size_t)l * PP_;     // l's 1024 W rows
    // phase 1: 1024 items = (sp in [0,32)) x (nq in [0,32))
    for (int i = 0; i < 4; ++i) {
      int idx = tid + i * 256;
      int sp = idx >> 5, nq = (idx & 31) * 4;
      const int s = grp * 64 + 2 * sp;        // even packed index
      const int blk = s >> 4, a = (s >> 2) & 3, c = (s >> 1) & 1;
      const int ij = IJTAB[blk], I = ij >> 3, J = ij & 7;
      const int rowX = (4 * I + a) * 32 + 4 * J + 2 * c;
      float4 s0 = *(const float4*)(W + (baseL + rowX)     * N_ + nq);
      float4 s1 = *(const float4*)(W + (baseL + rowX + 1) * N_ + nq);
      if (I != J) {
        const int rowY0 = (4 * J + 2 * c) * 32 + 4 * I + a;
        const float4 y0 = *(const float4*)(W + (baseL + rowY0)      * N_ + nq);
        const float4 y1 = *(const float4*)(W + (baseL + rowY0 + 32) * N_ + nq);
        s0.x += y0.x; s0.y += y0.y; s0.z += y0.z; s0.w += y0.w;
        s1.x += y1.x; s1.y += y1.y; s1.z += y1.z; s1.w += y1.w;
      }
      uint4 w;
      w.x = pk16(s0.x, s1.x);
      w.y = pk16(s0.y, s1.y);
      w.z = pk16(s0.z, s1.z);
      w.w = pk16(s0.w, s1.w);
      *(uint4*)&t32[sp * 133 + nq] = w;
    }
    __syncthreads();
    // phase 2: 1024 items = (n in [0,128)) x (cg in [0,8)): gather 4 u32 down
    // a column -> 8 consecutive packed s of row n
    for (int i = 0; i < 4; ++i) {
      int idx = tid + i * 256;
      int n = idx >> 3, cg = idx & 7;
      uint4 w;
      w.x = t32[(cg * 4 + 0) * 133 + n];
      w.y = t32[(cg * 4 + 1) * 133 + n];
      w.z = t32[(cg * 4 + 2) * 133 + n];
      w.w = t32[(cg * 4 + 3) * 133 + n];
      *(uint4*)(Wt + (size_t)n * KT_ + l * KP_ + grp * 64 + cg * 8) = w;
    }
  } else {
    const int mt = bid - 1152;            // 0..63, 16 b-rows each
    __shared__ float pl[512];             // 16 rows x 32 pert
    pl[tid]       = pert[(size_t)mt * 512 + tid];
    pl[tid + 256] = pert[(size_t)mt * 512 + tid + 256];
    __syncthreads();
    for (int r = 0; r < 5; ++r) {
      const int idx = tid + r * 256;      // (k8, lm): 72*16 = 1152 items
      if (idx < 1152) {
        const int k8 = idx >> 4, lm = idx & 15;
        const int blk = k8 >> 1, a0 = 2 * (k8 & 1);
        const int ij = IJTAB[blk], I = ij >> 3, J = ij & 7;
        const float* p = &pl[lm * 32];
        const float pi0 = p[4 * I + a0], pi1 = p[4 * I + a0 + 1];
        const float* pj = p + 4 * J;
        uint4 w;
        w.x = pk16(pi0 * pj[0], pi0 * pj[1]);
        w.y = pk16(pi0 * pj[2], pi0 * pj[3]);
        w.z = pk16(pi1 * pj[0], pi1 * pj[1]);
        w.w = pk16(pi1 * pj[2], pi1 * pj[3]);
        interf[(size_t)mt * 1152 + idx] = w;
      }
    }
  }
}

// ---------------------------------------------------------------------------
// GEMM (split-K, LPC=2): block (mtile 0..7, kchunk 0..63) computes the
// 128x128 tile  sum_{li=0,1} ctrl[:,2k+li] * (inter . Wsym_{2k+li}) over
// packed K=576 (9 its of BK=64), 4 waves in 2x2 (64x64 reg tile each), dual
// accumulators acc[2][4][4] so both l's share one barrier pair AND the
// l-independent A-fragments are loaded ONCE per it (halves inter_f traffic).
// A comes DIRECTLY global->VGPR from fragment-ordered inter_f (base+lane*16,
// dense 1 KB, L2-resident). B (Wt, shared by 4 waves) goes through two LDS
// buffers via gload16 with the XOR-chunk swizzle (chunk ^ (row&7)).
// ctrl is folded in the epilogue: out = c0*acc0 + c1*acc1 -> fp16 partials
// (16 MiB total). Grid = 512; same-kchunk mtiles sit 64 apart
// -> same XCD -> Wt slice fetched once per XCD (L2-hot from prep).
// (Round-2 note: explicit 2-phase dbuf pipelining of this loop measured
// neutral — implicit 2-blocks/CU wave overlap already covers the drain.)
// ---------------------------------------------------------------------------
__global__ __launch_bounds__(256, 2) void gemm_kernel(
    const unsigned short* __restrict__ Wt,
    const uint4* __restrict__ interf,
    const float* __restrict__ ctrl,
    _Float16* __restrict__ partials)
{
  __shared__ unsigned short Bsm[2][128 * 64];   // 2 x 16 KiB

  const int tid    = threadIdx.x;
  const int kchunk = blockIdx.x & 63;
  const int mtile  = blockIdx.x >> 6;        // 0..7
  const int m0     = mtile * 128;
  const int l0     = kchunk * 2;
  const int lane = tid & 63, wid = tid >> 6;
  const int wm = (wid >> 1) * 64, wn = (wid & 1) * 64;
  const int lm = lane & 15, kq = lane >> 4;

  // B staging geometry: lane covers (row = 8j+srow, chunk c8) in its segment
  const int srow = lane >> 3, c8 = lane & 7;
  const int sc = (c8 ^ srow) * 8;            // source elem offset (XOR swizzle)

  const unsigned short* bg0[4]; const unsigned short* bg1[4];
  unsigned short* bl0[4];       unsigned short* bl1[4];
  for (int j = 0; j < 4; ++j) {              // wave stages 32 B-rows per l
    const int rr = wid * 32 + j * 8;
    bg0[j] = Wt + (size_t)(rr + srow) * KT_ + (size_t)l0 * KP_ + sc;
    bg1[j] = bg0[j] + KP_;
    bl0[j] = &Bsm[0][rr * 64];
    bl1[j] = &Bsm[1][rr * 64];
  }

  // A fragment pointers: m-frag-block MT = mtile*8 + (wid>>1)*4 + tm
  const uint4* ap[4];
  for (int tm = 0; tm < 4; ++tm)
    ap[tm] = interf + (size_t)(mtile * 8 + (wid >> 1) * 4 + tm) * 1152 + lane;

  f32x4 acc[2][4][4];
  for (int li = 0; li < 2; ++li)
    for (int tm = 0; tm < 4; ++tm)
      for (int tn = 0; tn < 4; ++tn)
        acc[li][tm][tn] = (f32x4){0.f, 0.f, 0.f, 0.f};

  for (int it = 0; it < 9; ++it) {        // 9 * BK=64 = 576 = one packed l
    const int q0 = it * 64;
    __syncthreads();                      // previous iter's LDS reads done
    // A fragments (shared by both l's), global->VGPR
    f16x8 af[2][4];
    for (int ks = 0; ks < 2; ++ks)
      for (int tm = 0; tm < 4; ++tm)
        af[ks][tm] = *(const f16x8*)(ap[tm] + it * 128 + ks * 64);
    // B tiles for l0 and l1, global->LDS DMA
    for (int j = 0; j < 4; ++j) gload16(bl0[j], bg0[j] + q0);
    for (int j = 0; j < 4; ++j) gload16(bl1[j], bg1[j] + q0);
    __syncthreads();                      // drains vmcnt -> af + LDS valid
    for (int ks = 0; ks < 2; ++ks) {
      const int ch = (((ks * 4 + kq) ^ (lm & 7)) * 8);   // swizzled chunk
      for (int li = 0; li < 2; ++li) {
        f16x8 bfr[4];
        for (int t = 0; t < 4; ++t)
          bfr[t] = *(const f16x8*)&Bsm[li][(wn + t * 16 + lm) * 64 + ch];
        for (int tm = 0; tm < 4; ++tm)
          for (int t = 0; t < 4; ++t)
            acc[li][tm][t] = __builtin_amdgcn_mfma_f32_16x16x32_f16(
                af[ks][tm], bfr[t], acc[li][tm][t], 0, 0, 0);
      }
    }
  }

  // epilogue: fold ctrl for both l's, store fp16 partial tile (128x128).
  // C/D layout: row = kq*4+reg, col = lm (m89-verified).
  _Float16* pb = partials + (size_t)blockIdx.x * (128 * 128);
  for (int tm = 0; tm < 4; ++tm)
    for (int reg = 0; reg < 4; ++reg) {
      const int row = wm + tm * 16 + kq * 4 + reg;
      const float c0v = ctrl[(size_t)(m0 + row) * L_ + l0];
      const float c1v = ctrl[(size_t)(m0 + row) * L_ + l0 + 1];
      for (int tn = 0; tn < 4; ++tn)
        pb[row * 128 + wn + tn * 16 + lm] = (_Float16)(
            c0v * acc[0][tm][tn][reg] + c1v * acc[1][tm][tn][reg]);
    }
}

// ---------------------------------------------------------------------------
// Reduce (vectorized, G13): block b (0..1023): out[b][m] = bias[m] +
//   sum_{sp=0..63} partials[(b>>7)*64 + sp][b&127][m].
// Thread t = (sp0 = t>>4, cg = t&15): loads f16x8 (16 B/lane, 16 lanes cover
// one 256 B partial row-slice — fully coalesced) for sp = sp0 + 16i, i<4;
// accumulates 8 cols in fp32. LDS stage with 9-float pitch (breaks the
// 8-stride bank alias), then 128 threads finalize col t with bias.
// ---------------------------------------------------------------------------
__global__ __launch_bounds__(256) void reduce_kernel(
    const _Float16* __restrict__ partials, const float* __restrict__ bias,
    float* __restrict__ out)
{
  __shared__ float red[256][9];             // 9-pitch pad: write stride 9 banks
  const int bid = blockIdx.x;               // = b (output row)
  const int mtile = bid >> 7, row = bid & 127;
  const int t = threadIdx.x;
  const int sp0 = t >> 4;                   // 0..15
  const int cg  = t & 15;                   // col group: cols cg*8 .. cg*8+7
  const _Float16* base = partials + ((size_t)(mtile * 64)) * 16384
                         + row * 128 + cg * 8;
  float s[8] = {0.f, 0.f, 0.f, 0.f, 0.f, 0.f, 0.f, 0.f};
  #pragma unroll
  for (int i = 0; i < 4; ++i) {
    const int sp = sp0 + i * 16;
    f16x8 v = *(const f16x8*)(base + ((size_t)sp << 14));   // sp*128*128
    #pragma unroll
    for (int j = 0; j < 8; ++j) s[j] += (float)v[j];
  }
  #pragma unroll
  for (int j = 0; j < 8; ++j) red[t][j] = s[j];
  __syncthreads();
  if (t < 128) {
    // col t lives in source threads {s16*16 + (t>>3)} slot (t&7), s16=0..15
    float r = bias[t];
    #pragma unroll
    for (int s16 = 0; s16 < 16; ++s16)
      r += red[s16 * 16 + (t >> 3)][t & 7];
    out[(size_t)bid * N_ + t] = r;
  }
}

// ---------------------------------------------------------------------------
// Fallback (only if ws too small): exact fp32, slow but correct.
// ---------------------------------------------------------------------------
__global__ __launch_bounds__(256) void naive_kernel(
    const float* __restrict__ ctrl, const float* __restrict__ pert,
    const float* __restrict__ W, const float* __restrict__ bias,
    float* __restrict__ out)
{
  __shared__ float red[256];
  __shared__ float pl[P_];
  __shared__ float cl[L_];
  const int b = blockIdx.x, t = threadIdx.x;
  if (t < P_)  pl[t] = pert[(size_t)b * P_ + t];
  if (t < L_)  cl[t] = ctrl[(size_t)b * L_ + t];
  __syncthreads();
  const int m = t & 127, half = t >> 7;
  float acc = 0.f;
  for (int l = 0; l < L_; ++l) {
    float c = cl[l];
    for (int qq = half * 512; qq < half * 512 + 512; ++qq) {
      float x = c * pl[qq >> 5] * pl[qq & 31];
      acc += x * W[((size_t)l * PP_ + qq) * N_ + m];
    }
  }
  red[t] = acc;
  __syncthreads();
  if (t < 128) out[(size_t)b * 128 + t] = red[t] + red[t + 128] + bias[t];
}

extern "C" void kernel_launch(void* const* d_in, const int* in_sizes, int n_in,
                              void* d_out, int out_size, void* d_ws, size_t ws_size,
                              hipStream_t stream) {
  const float* ctrl = (const float*)d_in[0];   // (1024,128)
  const float* pert = (const float*)d_in[1];   // (1024,32)
  const float* W    = (const float*)d_in[2];   // (131072,128)
  const float* bias = (const float*)d_in[3];   // (128,)
  float* out = (float*)d_out;                  // (1024,128) fp32

  const size_t offWt    = 0;                        // 18 MiB: Wt fp16 (128,KT_)
  const size_t offInter = (size_t)18 << 20;         // 1.125 MiB: inter_f fp16
  const size_t offPart  = (size_t)20 << 20;         // 16 MiB: partials fp16
  const size_t needWs   = offPart + (size_t)512 * 128 * 128 * sizeof(_Float16);

  if (ws_size >= needWs) {
    unsigned short* Wt    = (unsigned short*)((char*)d_ws + offWt);
    uint4*          intf  = (uint4*)((char*)d_ws + offInter);
    _Float16*       parts = (_Float16*)((char*)d_ws + offPart);

    prep_kernel<<<1216, 256, 0, stream>>>(W, pert, Wt, intf);
    gemm_kernel<<<512, 256, 0, stream>>>(Wt, intf, ctrl, parts);
    reduce_kernel<<<1024, 256, 0, stream>>>(parts, bias, out);
  } else {
    naive_kernel<<<1024, 256, 0, stream>>>(ctrl, pert, W, bias, out);
  }
}